// Round 1
// baseline (867.442 us; speedup 1.0000x reference)
//
#include <hip/hip_runtime.h>

typedef unsigned short u16;
typedef __attribute__((ext_vector_type(8))) short short8;
typedef __attribute__((ext_vector_type(4))) float floatx4;

__device__ __forceinline__ u16 f2bf(float f){
  union { float f; unsigned u; } v; v.f = f;
  unsigned r = v.u + 0x7FFFu + ((v.u >> 16) & 1u);   // RNE
  return (u16)(r >> 16);
}
__device__ __forceinline__ float bf2f(u16 h){
  union { unsigned u; float f; } v; v.u = ((unsigned)h) << 16; return v.f;
}

// ---------------- prep: plane transpose [C=32][HW] f32 -> [HW][C] (f32 or bf16)
template<typename PT>
__global__ void ptrans_kernel(const float* __restrict__ src, PT* __restrict__ dst, int HW){
  __shared__ float tile[32][257];
  const int t = threadIdx.x;
  const size_t hw0 = (size_t)blockIdx.x * 256;
  #pragma unroll
  for (int c = 0; c < 32; c++) tile[c][t] = src[(size_t)c*HW + hw0 + t];
  __syncthreads();
  #pragma unroll
  for (int i = 0; i < 32; i++){
    int idx = i*256 + t;
    int j = idx >> 5, cc = idx & 31;
    float v = tile[cc][j];
    if constexpr (sizeof(PT) == 2) dst[(hw0 + j)*32 + cc] = f2bf(v);
    else                           dst[(hw0 + j)*32 + cc] = v;
  }
}

// ---------------- prep: weight transpose+convert: dst[m][n][k] = bf16(src[m][k][n])
__global__ void wconv_kernel(const float* __restrict__ src, u16* __restrict__ dst,
                             int fin, int fout, int total){
  int t = blockIdx.x*256 + threadIdx.x;
  if (t >= total) return;
  int per = fin * fout;
  int m = t / per, rem = t - m*per;
  int nn = rem / fin, kk = rem - nn*fin;
  dst[t] = f2bf(src[(size_t)m*per + (size_t)kk*fout + nn]);
}

// ---------------- interpolation
struct PlanePtrs { const void* p[9]; };

__device__ __forceinline__ void load8(const float* p, float* f){
  const float4* q = (const float4*)p;
  float4 a = q[0], b = q[1];
  f[0]=a.x; f[1]=a.y; f[2]=a.z; f[3]=a.w; f[4]=b.x; f[5]=b.y; f[6]=b.z; f[7]=b.w;
}
__device__ __forceinline__ void load8(const u16* p, float* f){
  short8 h = *(const short8*)p;
  #pragma unroll
  for (int e=0;e<8;e++) f[e] = bf2f((u16)h[e]);
}

template<typename PT, bool TR>
__global__ void interp_kernel(const float* __restrict__ pts, const float* __restrict__ aabb,
                              PlanePtrs pp, u16* __restrict__ feats, int N)
{
  int n = blockIdx.x*256 + threadIdx.x;
  if (n >= N) return;
  float xn[3];
  #pragma unroll
  for (int d=0; d<3; d++){
    float lo = aabb[d], hi = aabb[3+d];
    xn[d] = (pts[(size_t)n*3 + d] - lo) * (2.0f/(hi - lo)) - 1.0f;
  }
  const int c0s[3] = {0,0,1};
  const int c1s[3] = {1,2,2};
  #pragma unroll
  for (int s=0; s<3; s++){
    const int R = 128 << s;
    float prod[32];
    #pragma unroll
    for (int p=0; p<3; p++){
      float fx = (xn[c0s[p]] + 1.0f) * 0.5f * (float)(R-1);
      float fy = (xn[c1s[p]] + 1.0f) * 0.5f * (float)(R-1);
      float fx0 = fminf(fmaxf(floorf(fx), 0.0f), (float)(R-2));
      float fy0 = fminf(fmaxf(floorf(fy), 0.0f), (float)(R-2));
      int x0 = (int)fx0, y0 = (int)fy0;
      float wx = fx - fx0, wy = fy - fy0;
      float w00 = (1.0f-wx)*(1.0f-wy), w01 = wx*(1.0f-wy);
      float w10 = (1.0f-wx)*wy,        w11 = wx*wy;
      const PT* base = (const PT*)pp.p[s*3 + p];
      if constexpr (TR){
        const PT* b00 = base + ((size_t)y0*R + x0)*32;
        const PT* b10 = b00 + (size_t)R*32;
        #pragma unroll
        for (int v=0; v<4; v++){
          float f00[8], f01[8], f10[8], f11[8];
          load8(b00 + v*8,      f00);
          load8(b00 + 32 + v*8, f01);
          load8(b10 + v*8,      f10);
          load8(b10 + 32 + v*8, f11);
          #pragma unroll
          for (int e=0; e<8; e++){
            int c = v*8 + e;
            float val = f00[e]*w00 + f01[e]*w01 + f10[e]*w10 + f11[e]*w11;
            prod[c] = (p == 0) ? val : prod[c]*val;
          }
        }
      } else {
        const size_t HW = (size_t)R*R;
        const float* b00f = (const float*)base + (size_t)y0*R + x0;
        #pragma unroll 4
        for (int c=0; c<32; c++){
          const float* q = b00f + (size_t)c*HW;
          float val = q[0]*w00 + q[1]*w01 + q[R]*w10 + q[R+1]*w11;
          prod[c] = (p == 0) ? val : prod[c]*val;
        }
      }
    }
    #pragma unroll
    for (int v=0; v<4; v++){
      short8 pk;
      #pragma unroll
      for (int e=0; e<8; e++) pk[e] = (short)f2bf(prod[v*8+e]);
      *(short8*)(feats + (size_t)n*96 + s*32 + v*8) = pk;
    }
  }
}

// ---------------- fused MLP
// X in LDS: [64 rows][256 cols] bf16, byte addr = (row*512 + col*2) ^ ((row&7)<<4)
__device__ __forceinline__ void mm_tile(const u16* X, const u16* __restrict__ WT,
                                        int K, int colbase, int lane, floatx4 acc[4][4])
{
  const int lr = lane & 15, lg = lane >> 4;
  floatx4 zf = {0.0f, 0.0f, 0.0f, 0.0f};
  #pragma unroll
  for (int rf=0; rf<4; rf++)
    #pragma unroll
    for (int cf=0; cf<4; cf++)
      acc[rf][cf] = zf;
  const int ksteps = K >> 5;
  for (int ks=0; ks<ksteps; ks++){
    short8 a[4], b[4];
    #pragma unroll
    for (int rf=0; rf<4; rf++){
      int row = rf*16 + lr;
      int byt = (row*512 + (ks*32 + lg*8)*2) ^ ((row & 7) << 4);
      a[rf] = *(const short8*)((const char*)X + byt);
    }
    #pragma unroll
    for (int cf=0; cf<4; cf++){
      int col = colbase + cf*16 + lr;
      b[cf] = *(const short8*)(WT + (size_t)col*K + ks*32 + lg*8);
    }
    #pragma unroll
    for (int rf=0; rf<4; rf++)
      #pragma unroll
      for (int cf=0; cf<4; cf++)
        acc[rf][cf] = __builtin_amdgcn_mfma_f32_16x16x32_bf16(a[rf], b[cf], acc[rf][cf], 0, 0, 0);
  }
}

__global__ __launch_bounds__(256, 2) void mlp_kernel(
    const u16* __restrict__ feats,
    const u16* __restrict__ l0T, const u16* __restrict__ resT, const u16* __restrict__ l1T,
    const float* __restrict__ l0_b, const float* __restrict__ res_b, const float* __restrict__ l1_b,
    float* __restrict__ out)
{
  __shared__ u16 X[64*256];
  const int tid = threadIdx.x;
  const int wave = tid >> 6, lane = tid & 63;
  const int lr = lane & 15, lg = lane >> 4;
  const int n0 = blockIdx.x * 64;
  const int colbase = wave * 64;

  // stage feats tile: 64 rows x 96 cols bf16 (cols 96..255 unused by the K=96 layer)
  #pragma unroll
  for (int i=0; i<3; i++){
    int id = tid + i*256;
    int row = id / 12, sub = id - row*12;
    short8 v = *(const short8*)(feats + (size_t)(n0+row)*96 + sub*8);
    int byt = (row*512 + sub*16) ^ ((row & 7) << 4);
    *(short8*)((char*)X + byt) = v;
  }
  __syncthreads();

  floatx4 acc[4][4];
  float resv[4][4][4];

  // ---- L0: K=96, no activation
  mm_tile(X, l0T, 96, colbase, lane, acc);
  __syncthreads();
  #pragma unroll
  for (int cf=0; cf<4; cf++){
    int col = colbase + cf*16 + lr;
    float bb = l0_b[col];
    #pragma unroll
    for (int rf=0; rf<4; rf++)
      #pragma unroll
      for (int r=0; r<4; r++){
        int row = rf*16 + lg*4 + r;
        int byt = (row*512 + col*2) ^ ((row&7)<<4);
        *(u16*)((char*)X + byt) = f2bf(acc[rf][cf][r] + bb);
      }
  }
  __syncthreads();

  // ---- 3 ResBlocks
  for (int rb=0; rb<3; rb++){
    const u16* W0 = resT + (size_t)(rb*3+0)*65536;
    const u16* W1 = resT + (size_t)(rb*3+1)*65536;
    const u16* W2 = resT + (size_t)(rb*3+2)*65536;
    const float* b0 = res_b + (rb*3+0)*256;
    const float* b1 = res_b + (rb*3+1)*256;
    const float* b2 = res_b + (rb*3+2)*256;

    // z = relu(x@W0+b0); res = x + z  (res kept in regs AND written to X)
    mm_tile(X, W0, 256, colbase, lane, acc);
    __syncthreads();
    #pragma unroll
    for (int cf=0; cf<4; cf++){
      int col = colbase + cf*16 + lr;
      float bb = b0[col];
      #pragma unroll
      for (int rf=0; rf<4; rf++)
        #pragma unroll
        for (int r=0; r<4; r++){
          int row = rf*16 + lg*4 + r;
          int byt = (row*512 + col*2) ^ ((row&7)<<4);
          float xo = bf2f(*(const u16*)((const char*)X + byt));
          float v = xo + fmaxf(acc[rf][cf][r] + bb, 0.0f);
          resv[rf][cf][r] = v;
          *(u16*)((char*)X + byt) = f2bf(v);
        }
    }
    __syncthreads();

    // x = relu(res@W1+b1)
    mm_tile(X, W1, 256, colbase, lane, acc);
    __syncthreads();
    #pragma unroll
    for (int cf=0; cf<4; cf++){
      int col = colbase + cf*16 + lr;
      float bb = b1[col];
      #pragma unroll
      for (int rf=0; rf<4; rf++)
        #pragma unroll
        for (int r=0; r<4; r++){
          int row = rf*16 + lg*4 + r;
          int byt = (row*512 + col*2) ^ ((row&7)<<4);
          *(u16*)((char*)X + byt) = f2bf(fmaxf(acc[rf][cf][r] + bb, 0.0f));
        }
    }
    __syncthreads();

    // x = relu(x@W2+b2) + res
    mm_tile(X, W2, 256, colbase, lane, acc);
    __syncthreads();
    #pragma unroll
    for (int cf=0; cf<4; cf++){
      int col = colbase + cf*16 + lr;
      float bb = b2[col];
      #pragma unroll
      for (int rf=0; rf<4; rf++)
        #pragma unroll
        for (int r=0; r<4; r++){
          int row = rf*16 + lg*4 + r;
          int byt = (row*512 + col*2) ^ ((row&7)<<4);
          *(u16*)((char*)X + byt) = f2bf(fmaxf(acc[rf][cf][r] + bb, 0.0f) + resv[rf][cf][r]);
        }
    }
    __syncthreads();
  }

  // ---- final: 256 -> 16, sigmoid. Each wave: 16 rows x 16 cols.
  floatx4 accf = {0.0f, 0.0f, 0.0f, 0.0f};
  #pragma unroll
  for (int ks=0; ks<8; ks++){
    int row = wave*16 + lr;
    int byt = (row*512 + (ks*32 + lg*8)*2) ^ ((row&7)<<4);
    short8 a = *(const short8*)((const char*)X + byt);
    short8 b = *(const short8*)(l1T + (size_t)lr*256 + ks*32 + lg*8);
    accf = __builtin_amdgcn_mfma_f32_16x16x32_bf16(a, b, accf, 0, 0, 0);
  }
  float bo = l1_b[lr];
  #pragma unroll
  for (int r=0; r<4; r++){
    int row = wave*16 + lg*4 + r;
    float v = accf[r] + bo;
    v = 1.0f / (1.0f + __expf(-v));
    out[(size_t)(n0+row)*16 + lr] = v;
  }
}

// ---------------- host
extern "C" void kernel_launch(void* const* d_in, const int* in_sizes, int n_in,
                              void* d_out, int out_size, void* d_ws, size_t ws_size,
                              hipStream_t stream)
{
  const float* pts  = (const float*)d_in[0];
  const float* aabb = (const float*)d_in[1];
  const float* l0_w = (const float*)d_in[11];
  const float* l0_b = (const float*)d_in[12];
  const float* res_w= (const float*)d_in[13];
  const float* res_b= (const float*)d_in[14];
  const float* l1_w = (const float*)d_in[15];
  const float* l1_b = (const float*)d_in[16];
  const int N = in_sizes[0] / 3;

  char* ws = (char*)d_ws;
  const size_t woff_l0  = 0;                          // 256*96*2   = 49152
  const size_t woff_res = 49152;                      // 9*65536*2  = 1179648
  const size_t woff_l1  = woff_res + 9*65536*2;       // 16*256*2   = 8192
  const size_t foff     = woff_l1 + 8192;             // feats: N*96*2
  const size_t poff     = foff + (size_t)N*96*2;

  static const int HWs[3] = {128*128, 256*256, 512*512};
  size_t pel[9]; size_t tot = 0;
  for (int s=0;s<3;s++) for (int p=0;p<3;p++){ pel[s*3+p] = tot; tot += (size_t)HWs[s]*32; }

  int mode;
  if      (ws_size >= poff + tot*4) mode = 2;   // fp32 transposed planes
  else if (ws_size >= poff + tot*2) mode = 1;   // bf16 transposed planes
  else                              mode = 0;   // gather from original layout

  // weights -> [out][in] bf16
  wconv_kernel<<<(24576+255)/256,  256, 0, stream>>>(l0_w, (u16*)(ws+woff_l0), 96, 256, 24576);
  wconv_kernel<<<(589824+255)/256, 256, 0, stream>>>(res_w,(u16*)(ws+woff_res),256, 256, 589824);
  wconv_kernel<<<(4096+255)/256,   256, 0, stream>>>(l1_w, (u16*)(ws+woff_l1), 256, 16,  4096);

  PlanePtrs pp;
  if (mode == 2){
    float* pbase = (float*)(ws + poff);
    for (int i=0;i<9;i++){
      int s = i/3;
      ptrans_kernel<float><<<HWs[s]/256, 256, 0, stream>>>((const float*)d_in[2+i], pbase + pel[i], HWs[s]);
      pp.p[i] = pbase + pel[i];
    }
    interp_kernel<float,true><<<(N+255)/256, 256, 0, stream>>>(pts, aabb, pp, (u16*)(ws+foff), N);
  } else if (mode == 1){
    u16* pbase = (u16*)(ws + poff);
    for (int i=0;i<9;i++){
      int s = i/3;
      ptrans_kernel<u16><<<HWs[s]/256, 256, 0, stream>>>((const float*)d_in[2+i], pbase + pel[i], HWs[s]);
      pp.p[i] = pbase + pel[i];
    }
    interp_kernel<u16,true><<<(N+255)/256, 256, 0, stream>>>(pts, aabb, pp, (u16*)(ws+foff), N);
  } else {
    for (int i=0;i<9;i++) pp.p[i] = d_in[2+i];
    interp_kernel<float,false><<<(N+255)/256, 256, 0, stream>>>(pts, aabb, pp, (u16*)(ws+foff), N);
  }

  mlp_kernel<<<N/64, 256, 0, stream>>>((const u16*)(ws+foff),
      (const u16*)(ws+woff_l0), (const u16*)(ws+woff_res), (const u16*)(ws+woff_l1),
      l0_b, res_b, l1_b, (float*)d_out);
}